// Round 4
// baseline (576.733 us; speedup 1.0000x reference)
//
#include <hip/hip_runtime.h>
#include <stdint.h>
#include <stddef.h>

// HardNegativeMiningLoss on MI355X (B=8192, D=512, K=16, TEMP=0.07, labels<2048).
// kinit -> kconv(bf16) -> khist -> kprefix -> kscatter -> kpos2 -> kgemm (LDS-free:
// row-panel in VGPRs, col-fragments streamed from L2, per-lane semi top-16 mining)
// -> kfin (merge partials, masked LSE; fallback detect) -> kfall (rare exact
// all-negatives fallback) -> kout.

#define TEMPV 0.07f
#define NEGV -1e30f

typedef short v8s __attribute__((ext_vector_type(8)));
typedef float v4f __attribute__((ext_vector_type(4)));

__device__ __forceinline__ short f2bf(float f) {
  unsigned u = __float_as_uint(f);
  unsigned r = (u + 0x7fffu + ((u >> 16) & 1u)) >> 16;  // RNE
  return (short)r;
}
__device__ __forceinline__ float bf2f(short s) {
  return __uint_as_float(((unsigned)(unsigned short)s) << 16);
}

// ---- Batcher odd-even mergesort network for 16 elements (63 comparators) ----
struct SNet { unsigned char a[64]; unsigned char b[64]; int n; };
constexpr SNet mknet16() {
  SNet t{}; t.n = 0;
  for (int p = 1; p < 16; p <<= 1)
    for (int k = p; k >= 1; k >>= 1)
      for (int j = k % p; j + k < 16; j += 2 * k)
        for (int i = 0; i < k; ++i) {
          int x = i + j, y = i + j + k;
          if (y < 16 && (x / (2 * p)) == (y / (2 * p))) {
            t.a[t.n] = (unsigned char)x; t.b[t.n] = (unsigned char)y; ++t.n;
          }
        }
  return t;
}
constexpr SNet NET16 = mknet16();
constexpr int NETN = NET16.n;

__device__ __forceinline__ void sort16d(float (&V)[16]) {
#pragma unroll
  for (int c = 0; c < NETN; ++c) {
    const int x = NET16.a[c], y = NET16.b[c];
    float hi = fmaxf(V[x], V[y]);
    float lo = fminf(V[x], V[y]);
    V[x] = hi; V[y] = lo;
  }
}

// clean a bitonic 16-seq into descending order
__device__ __forceinline__ void clean16d(float (&V)[16]) {
#pragma unroll
  for (int s = 8; s >= 1; s >>= 1) {
#pragma unroll
    for (int i = 0; i < 16; ++i) {
      if ((i & s) == 0) {
        float hi = fmaxf(V[i], V[i + s]);
        float lo = fminf(V[i], V[i + s]);
        V[i] = hi; V[i + s] = lo;
      }
    }
  }
}

// R = top16(R ∪ M), both desc sorted; in-place, no temp array
__device__ __forceinline__ void mergeld(float (&R)[16], const float (&M)[16]) {
#pragma unroll
  for (int i = 0; i < 8; ++i) {
    float a = fmaxf(M[i], R[15 - i]);
    float b = fmaxf(M[15 - i], R[i]);
    R[i] = a; R[15 - i] = b;
  }
  clean16d(R);
}

// merge my desc-16 with xor-partner lane's desc-16 (in place, pairwise shfl)
__device__ __forceinline__ void xmerge16(float (&M)[16], int mask) {
#pragma unroll
  for (int i = 0; i < 8; ++i) {
    float pa = __shfl_xor(M[15 - i], mask);
    float pb = __shfl_xor(M[i], mask);
    M[i] = fmaxf(M[i], pa);
    M[15 - i] = fmaxf(M[15 - i], pb);
  }
  clean16d(M);
}

// ascending top-16 insert list (kfall only): call when v > L[0]
__device__ __forceinline__ void ins16(float (&L)[16], float v) {
#pragma unroll
  for (int k = 0; k < 15; ++k) {
    float lo = fminf(v, L[k + 1]);
    float hi = fmaxf(v, L[k + 1]);
    L[k] = lo;
    v = hi;
  }
  L[15] = v;
}

// ---------------- small setup kernels ----------------
__global__ void kinit(int* hist, int* cur, float* lsum, int* nval, int* fbcnt) {
  int i = blockIdx.x * blockDim.x + threadIdx.x;
  if (i < 2048) { hist[i] = 0; cur[i] = 0; }
  if (i == 0) { *lsum = 0.f; *nval = 0; *fbcnt = 0; }
}

__global__ void kconv(const float* __restrict__ emb, short* __restrict__ emb16) {
  int i = (blockIdx.x * 256 + threadIdx.x) * 4;
  float4 v = *(const float4*)(emb + i);
  short4 s;
  s.x = f2bf(v.x); s.y = f2bf(v.y); s.z = f2bf(v.z); s.w = f2bf(v.w);
  *(short4*)(emb16 + i) = s;
}

__global__ void khist(const int* __restrict__ lab, int* hist) {
  int i = blockIdx.x * 256 + threadIdx.x;
  if (i < 8192) atomicAdd(&hist[lab[i]], 1);
}

__global__ __launch_bounds__(256) void kprefix(const int* __restrict__ hist,
                                               int* __restrict__ start) {
  __shared__ int part[256];
  int t = threadIdx.x;
  int v[8], loc[8], s = 0;
#pragma unroll
  for (int k = 0; k < 8; ++k) v[k] = hist[t * 8 + k];
#pragma unroll
  for (int k = 0; k < 8; ++k) { loc[k] = s; s += v[k]; }
  part[t] = s;
  __syncthreads();
  for (int off = 1; off < 256; off <<= 1) {
    int x = (t >= off) ? part[t - off] : 0;
    __syncthreads();
    part[t] += x;
    __syncthreads();
  }
  int base = (t > 0) ? part[t - 1] : 0;
#pragma unroll
  for (int k = 0; k < 8; ++k) start[t * 8 + k] = base + loc[k];
}

__global__ void kscatter(const int* __restrict__ lab, const int* __restrict__ start,
                         int* cur, int* __restrict__ rows) {
  int i = blockIdx.x * 256 + threadIdx.x;
  if (i < 8192) {
    int li = lab[i];
    int p = atomicAdd(&cur[li], 1);
    rows[start[li] + p] = i;
  }
}

__global__ __launch_bounds__(256) void kpos2(const short* __restrict__ emb16,
                                             const int* __restrict__ lab,
                                             const int* __restrict__ hist,
                                             const int* __restrict__ start,
                                             const int* __restrict__ rows,
                                             float* __restrict__ pmin,
                                             float* __restrict__ pterm,
                                             int* __restrict__ valid) {
  int t = threadIdx.x;
  int wv = t >> 6, lane = t & 63;
  int i = blockIdx.x * 4 + wv;
  int li = lab[i];
  int s0 = start[li], c = hist[li];
  float ei[8];
  v8s e = *(const v8s*)(emb16 + (size_t)i * 512 + lane * 8);
#pragma unroll
  for (int k = 0; k < 8; ++k) ei[k] = bf2f(e[k]);
  float smin = 1e30f, ssum = 0.f;
  for (int k = 0; k < c; ++k) {
    int j = rows[s0 + k];
    if (j == i) continue;
    v8s f = *(const v8s*)(emb16 + (size_t)j * 512 + lane * 8);
    float s = 0.f;
#pragma unroll
    for (int q = 0; q < 8; ++q) s += ei[q] * bf2f(f[q]);
#pragma unroll
    for (int off = 32; off; off >>= 1) s += __shfl_xor(s, off);
    smin = fminf(smin, s);
    ssum += s;
  }
  if (lane == 0) {
    int pc = c - 1, nc = 8192 - c;
    pmin[i] = smin;                                   // +1e30 when no positives
    pterm[i] = ssum / (float)(pc > 0 ? pc : 1) / TEMPV;
    valid[i] = (pc > 0 && nc > 0) ? 1 : 0;
  }
}

// ---------------- main mining GEMM (LDS-free) ----------------
// Grid 512 = 64 row-blocks(BM=128) x 8 col-blocks (1024 cols; cb=bid&7 -> XCD).
// 4 waves x 32 rows each (fi=0,1 -> rows wv*32+fi*16+l15). Row-panel b-operands
// live in 128 VGPRs (2 rows x K=512). Col a-fragments are loaded straight from
// L2 (panel is 1MB, XCD-resident; L1 filters the 4-wave reuse). No LDS, no
// barriers. acc[mi][fi]: row = wv*32+fi*16+l15 (one row per lane per fi),
// col = colstart + mi*16 + l4*4 + r -> per-lane register semi top-16 mining.
__global__ __launch_bounds__(256, 2) void kgemm(const short* __restrict__ emb16,
                                                const int* __restrict__ lab,
                                                const float* __restrict__ pminA,
                                                float* __restrict__ Lsemi) {
  int t = threadIdx.x;
  int bid = blockIdx.x;
  int rb = bid >> 3, cb = bid & 7;
  int rowbase = rb * 128;
  int colblock = cb * 1024;

  int wv = t >> 6, l = t & 63;
  int l15 = l & 15, l4 = l >> 4;

  int rlab[2]; float pm[2];
  v8s brg[2][16];
#pragma unroll
  for (int fi = 0; fi < 2; ++fi) {
    int row = rowbase + wv * 32 + fi * 16 + l15;
    rlab[fi] = lab[row];
    pm[fi] = pminA[row];
#pragma unroll
    for (int kc = 0; kc < 16; ++kc)
      brg[fi][kc] = *(const v8s*)(emb16 + (size_t)row * 512 + kc * 32 + l4 * 8);
  }

  float RS[2][16];
#pragma unroll
  for (int fi = 0; fi < 2; ++fi)
#pragma unroll
    for (int k = 0; k < 16; ++k) RS[fi][k] = NEGV;

  for (int tile = 0; tile < 16; ++tile) {
    int colstart = colblock + tile * 64;
    // prefetch this tile's column labels (used in mining below)
    int lc[4][4];
#pragma unroll
    for (int mm = 0; mm < 4; ++mm) {
      int4 q = *(const int4*)&lab[colstart + mm * 16 + l4 * 4];
      lc[mm][0] = q.x; lc[mm][1] = q.y; lc[mm][2] = q.z; lc[mm][3] = q.w;
    }

    v4f acc[4][2];
#pragma unroll
    for (int mi = 0; mi < 4; ++mi)
#pragma unroll
      for (int fi = 0; fi < 2; ++fi) acc[mi][fi] = (v4f)0.f;

    // a-frag base pointers: col = colstart + mi*16 + l15, k-slice starts at l4*8
    const short* abase[4];
#pragma unroll
    for (int mi = 0; mi < 4; ++mi)
      abase[mi] = emb16 + (size_t)(colstart + mi * 16 + l15) * 512 + l4 * 8;

#pragma unroll
    for (int ks = 0; ks < 8; ++ks) {
      v8s a[2][4];
#pragma unroll
      for (int h = 0; h < 2; ++h)
#pragma unroll
        for (int mi = 0; mi < 4; ++mi)
          a[h][mi] = *(const v8s*)(abase[mi] + ks * 64 + h * 32);
#pragma unroll
      for (int h = 0; h < 2; ++h)
#pragma unroll
        for (int mi = 0; mi < 4; ++mi)
#pragma unroll
          for (int fi = 0; fi < 2; ++fi)
            acc[mi][fi] = __builtin_amdgcn_mfma_f32_16x16x32_bf16(
                a[h][mi], brg[fi][ks * 2 + h], acc[mi][fi], 0, 0, 0);
    }

    // ---- per-lane semi-hard mining (one 16-value batch per fi) ----
#pragma unroll
    for (int fi = 0; fi < 2; ++fi) {
      float S[16];
#pragma unroll
      for (int j = 0; j < 16; ++j) {
        const int mi = j >> 2, r = j & 3;
        float v = acc[mi][fi][r];
        bool keep = (lc[mi][r] != rlab[fi]) && (v < pm[fi]);
        S[j] = keep ? v : NEGV;
      }
      sort16d(S);
      mergeld(RS[fi], S);
    }
  }

  // merge the 4 lanes (l4 groups) holding the same row, then write partials
#pragma unroll
  for (int fi = 0; fi < 2; ++fi) {
    xmerge16(RS[fi], 16);
    xmerge16(RS[fi], 32);
    if (l4 == 0) {
      int myrow = rowbase + wv * 32 + fi * 16 + l15;
      size_t o = ((size_t)cb * 8192 + myrow) * 16;
#pragma unroll
      for (int k = 0; k < 4; ++k)
        *(float4*)&Lsemi[o + k * 4] = make_float4(RS[fi][k * 4], RS[fi][k * 4 + 1],
                                                  RS[fi][k * 4 + 2], RS[fi][k * 4 + 3]);
    }
  }
}

// merge 8 col-block semi partials, masked LSE, detect fallback rows, reduce
__global__ __launch_bounds__(256) void kfin(const float* __restrict__ Lsemi,
                                            const float* __restrict__ pterm,
                                            const int* __restrict__ valid,
                                            float* lsum, int* nval,
                                            int* fbcnt, int* fbrows) {
  int i = blockIdx.x * 256 + threadIdx.x;
  float S[16], M[16];
#pragma unroll
  for (int k = 0; k < 16; ++k) S[k] = Lsemi[(size_t)i * 16 + k];
  for (int c = 1; c < 8; ++c) {
    size_t o = ((size_t)c * 8192 + i) * 16;
#pragma unroll
    for (int k = 0; k < 16; ++k) M[k] = Lsemi[o + k];
    mergeld(S, M);
  }
  int vd = valid[i];
  bool hs = S[0] > -1e29f;
  float li = 0.f;
  if (vd && !hs) {
    // rare exact-fallback row: needs top-16 over ALL negatives (kfall)
    int idx = atomicAdd(fbcnt, 1);
    fbrows[idx] = i;
  } else if (vd) {
    float m = S[0] / TEMPV;
    float se = 0.f;
#pragma unroll
    for (int k = 0; k < 16; ++k)
      if (S[k] > -1e29f) se += expf(S[k] / TEMPV - m);
    li = m + logf(se) - pterm[i];
  }
#pragma unroll
  for (int off = 32; off; off >>= 1) {
    li += __shfl_xor(li, off);
    vd += __shfl_xor(vd, off);
  }
  __shared__ float rsd[4];
  __shared__ int rid[4];
  int wv = threadIdx.x >> 6;
  if ((threadIdx.x & 63) == 0) { rsd[wv] = li; rid[wv] = vd; }
  __syncthreads();
  if (threadIdx.x == 0) {
    atomicAdd(lsum, rsd[0] + rsd[1] + rsd[2] + rsd[3]);
    atomicAdd(nval, rid[0] + rid[1] + rid[2] + rid[3]);
  }
}

// exact all-negatives top-16 for rows with no semi-hard negatives (expected: none)
__global__ __launch_bounds__(256) void kfall(const short* __restrict__ emb16,
                                             const int* __restrict__ lab,
                                             const int* __restrict__ fbcnt,
                                             const int* __restrict__ fbrows,
                                             const float* __restrict__ pterm,
                                             float* lsum) {
  int nfb = *fbcnt;
  __shared__ short remb[512];
  __shared__ float wl[4][16];
  int t = threadIdx.x;
  int wv = t >> 6, lane = t & 63;
  for (int idx = blockIdx.x; idx < nfb; idx += gridDim.x) {
    int row = fbrows[idx];
    int rl = lab[row];
    if (t < 64) *(v8s*)&remb[t * 8] = *(const v8s*)(emb16 + (size_t)row * 512 + t * 8);
    __syncthreads();
    float L[16];
#pragma unroll
    for (int k = 0; k < 16; ++k) L[k] = NEGV;  // ascending list (L[0]=min)
    for (int c = t; c < 8192; c += 256) {
      if (lab[c] == rl) continue;  // excludes positives and self
      float s = 0.f;
      for (int q = 0; q < 64; ++q) {
        v8s e = *(const v8s*)(emb16 + (size_t)c * 512 + q * 8);
        v8s r = *(const v8s*)&remb[q * 8];
#pragma unroll
        for (int z = 0; z < 8; ++z) s += bf2f(e[z]) * bf2f(r[z]);
      }
      if (s > L[0]) ins16(L, s);
    }
    // convert ascending->descending
    float D[16];
#pragma unroll
    for (int k = 0; k < 16; ++k) D[k] = L[15 - k];
    xmerge16(D, 1); xmerge16(D, 2); xmerge16(D, 4);
    xmerge16(D, 8); xmerge16(D, 16); xmerge16(D, 32);
    if (lane == 0) {
#pragma unroll
      for (int k = 0; k < 16; ++k) wl[wv][k] = D[k];
    }
    __syncthreads();
    if (t == 0) {
      float R[16], M[16];
#pragma unroll
      for (int k = 0; k < 16; ++k) R[k] = wl[0][k];
      for (int w = 1; w < 4; ++w) {
#pragma unroll
        for (int k = 0; k < 16; ++k) M[k] = wl[w][k];
        mergeld(R, M);
      }
      float m = R[0] / TEMPV;
      float se = 0.f;
#pragma unroll
      for (int k = 0; k < 16; ++k)
        if (R[k] > -1e29f) se += expf(R[k] / TEMPV - m);
      float lse = m + logf(se);
      atomicAdd(lsum, lse - pterm[row]);
    }
    __syncthreads();
  }
}

__global__ void kout(const float* lsum, const int* nval, float* out) {
  if (threadIdx.x == 0 && blockIdx.x == 0)
    out[0] = lsum[0] / (float)(nval[0] > 0 ? nval[0] : 1);
}

extern "C" void kernel_launch(void* const* d_in, const int* in_sizes, int n_in,
                              void* d_out, int out_size, void* d_ws, size_t ws_size,
                              hipStream_t stream) {
  const float* emb = (const float*)d_in[0];
  const int* lab = (const int*)d_in[1];
  float* out = (float*)d_out;

  char* wsb = (char*)d_ws;
  short* emb16 = (short*)wsb;                       // 8,388,608
  int* hist = (int*)(wsb + 8388608);                // 8,192
  int* cur = (int*)(wsb + 8396800);                 // 8,192
  int* start = (int*)(wsb + 8404992);               // 8,192
  int* rows = (int*)(wsb + 8413184);                // 32,768
  float* pmin = (float*)(wsb + 8445952);            // 32,768
  float* pterm = (float*)(wsb + 8478720);           // 32,768
  int* valid = (int*)(wsb + 8511488);               // 32,768
  float* LsemiW = (float*)(wsb + 8544256);          // 4,194,304
  int* fbcnt = (int*)(wsb + 12738560);              // 4 (+pad)
  int* fbrows = (int*)(wsb + 12738624);             // 32,768
  float* lsum = (float*)(wsb + 12771392);           // 4
  int* nval = (int*)(wsb + 12771396);               // 4

  kinit<<<8, 256, 0, stream>>>(hist, cur, lsum, nval, fbcnt);
  kconv<<<4096, 256, 0, stream>>>(emb, emb16);
  khist<<<32, 256, 0, stream>>>(lab, hist);
  kprefix<<<1, 256, 0, stream>>>(hist, start);
  kscatter<<<32, 256, 0, stream>>>(lab, start, cur, rows);
  kpos2<<<2048, 256, 0, stream>>>(emb16, lab, hist, start, rows, pmin, pterm, valid);
  kgemm<<<512, 256, 0, stream>>>(emb16, lab, pmin, LsemiW);
  kfin<<<32, 256, 0, stream>>>(LsemiW, pterm, valid, lsum, nval, fbcnt, fbrows);
  kfall<<<32, 256, 0, stream>>>(emb16, lab, fbcnt, fbrows, pterm, lsum);
  kout<<<1, 64, 0, stream>>>(lsum, nval, out);
}

// Round 5
// 236.081 us; speedup vs baseline: 2.4429x; 2.4429x over previous
//
#include <hip/hip_runtime.h>
#include <stdint.h>
#include <stddef.h>

// HardNegativeMiningLoss on MI355X (B=8192, D=512, K=16, TEMP=0.07, labels<2048).
// kinit -> kconv(bf16) -> khist -> kprefix -> kscatter -> kpos2 -> kgemm (bf16 MFMA,
// R-panel LDS-resident, per-lane register SEMI top-16 mining) -> kfin (merge, LSE,
// fallback detect) -> kfallA/kfallB (parallel exact all-negatives fallback) -> kout.

#define TEMPV 0.07f
#define NEGV -1e30f

typedef short v8s __attribute__((ext_vector_type(8)));
typedef float v4f __attribute__((ext_vector_type(4)));

__device__ __forceinline__ short f2bf(float f) {
  unsigned u = __float_as_uint(f);
  unsigned r = (u + 0x7fffu + ((u >> 16) & 1u)) >> 16;  // RNE
  return (short)r;
}
__device__ __forceinline__ float bf2f(short s) {
  return __uint_as_float(((unsigned)(unsigned short)s) << 16);
}

__device__ __forceinline__ void gload16(const void* g, void* l) {
  __builtin_amdgcn_global_load_lds((const __attribute__((address_space(1))) unsigned*)g,
                                   (__attribute__((address_space(3))) unsigned*)l, 16, 0, 0);
}

// ---- Batcher odd-even mergesort network for 16 elements (63 comparators) ----
struct SNet { unsigned char a[64]; unsigned char b[64]; int n; };
constexpr SNet mknet16() {
  SNet t{}; t.n = 0;
  for (int p = 1; p < 16; p <<= 1)
    for (int k = p; k >= 1; k >>= 1)
      for (int j = k % p; j + k < 16; j += 2 * k)
        for (int i = 0; i < k; ++i) {
          int x = i + j, y = i + j + k;
          if (y < 16 && (x / (2 * p)) == (y / (2 * p))) {
            t.a[t.n] = (unsigned char)x; t.b[t.n] = (unsigned char)y; ++t.n;
          }
        }
  return t;
}
constexpr SNet NET16 = mknet16();
constexpr int NETN = NET16.n;

__device__ __forceinline__ void sort16d(float (&V)[16]) {
#pragma unroll
  for (int c = 0; c < NETN; ++c) {
    const int x = NET16.a[c], y = NET16.b[c];
    float hi = fmaxf(V[x], V[y]);
    float lo = fminf(V[x], V[y]);
    V[x] = hi; V[y] = lo;
  }
}

// clean a bitonic 16-seq into descending order
__device__ __forceinline__ void clean16d(float (&V)[16]) {
#pragma unroll
  for (int s = 8; s >= 1; s >>= 1) {
#pragma unroll
    for (int i = 0; i < 16; ++i) {
      if ((i & s) == 0) {
        float hi = fmaxf(V[i], V[i + s]);
        float lo = fminf(V[i], V[i + s]);
        V[i] = hi; V[i + s] = lo;
      }
    }
  }
}

// R = top16(R ∪ M), both desc sorted; in-place
__device__ __forceinline__ void mergeld(float (&R)[16], const float (&M)[16]) {
#pragma unroll
  for (int i = 0; i < 8; ++i) {
    float a = fmaxf(M[i], R[15 - i]);
    float b = fmaxf(M[15 - i], R[i]);
    R[i] = a; R[15 - i] = b;
  }
  clean16d(R);
}

// merge my desc-16 with xor-partner lane's desc-16 (both get top-16 of union)
__device__ __forceinline__ void xmerge16(float (&M)[16], int mask) {
#pragma unroll
  for (int i = 0; i < 8; ++i) {
    float pa = __shfl_xor(M[15 - i], mask);
    float pb = __shfl_xor(M[i], mask);
    M[i] = fmaxf(M[i], pa);
    M[15 - i] = fmaxf(M[15 - i], pb);
  }
  clean16d(M);
}

// ascending top-16 insert list (serial guard path only): call when v > L[0]
__device__ __forceinline__ void ins16(float (&L)[16], float v) {
#pragma unroll
  for (int k = 0; k < 15; ++k) {
    float lo = fminf(v, L[k + 1]);
    float hi = fmaxf(v, L[k + 1]);
    L[k] = lo;
    v = hi;
  }
  L[15] = v;
}

// ---------------- small setup kernels ----------------
__global__ void kinit(int* hist, int* cur, float* lsum, int* nval, int* fbcnt) {
  int i = blockIdx.x * blockDim.x + threadIdx.x;
  if (i < 2048) { hist[i] = 0; cur[i] = 0; }
  if (i == 0) { *lsum = 0.f; *nval = 0; *fbcnt = 0; }
}

__global__ void kconv(const float* __restrict__ emb, short* __restrict__ emb16) {
  int i = (blockIdx.x * 256 + threadIdx.x) * 4;
  float4 v = *(const float4*)(emb + i);
  short4 s;
  s.x = f2bf(v.x); s.y = f2bf(v.y); s.z = f2bf(v.z); s.w = f2bf(v.w);
  *(short4*)(emb16 + i) = s;
}

__global__ void khist(const int* __restrict__ lab, int* hist) {
  int i = blockIdx.x * 256 + threadIdx.x;
  if (i < 8192) atomicAdd(&hist[lab[i]], 1);
}

__global__ __launch_bounds__(256) void kprefix(const int* __restrict__ hist,
                                               int* __restrict__ start) {
  __shared__ int part[256];
  int t = threadIdx.x;
  int v[8], loc[8], s = 0;
#pragma unroll
  for (int k = 0; k < 8; ++k) v[k] = hist[t * 8 + k];
#pragma unroll
  for (int k = 0; k < 8; ++k) { loc[k] = s; s += v[k]; }
  part[t] = s;
  __syncthreads();
  for (int off = 1; off < 256; off <<= 1) {
    int x = (t >= off) ? part[t - off] : 0;
    __syncthreads();
    part[t] += x;
    __syncthreads();
  }
  int base = (t > 0) ? part[t - 1] : 0;
#pragma unroll
  for (int k = 0; k < 8; ++k) start[t * 8 + k] = base + loc[k];
}

__global__ void kscatter(const int* __restrict__ lab, const int* __restrict__ start,
                         int* cur, int* __restrict__ rows) {
  int i = blockIdx.x * 256 + threadIdx.x;
  if (i < 8192) {
    int li = lab[i];
    int p = atomicAdd(&cur[li], 1);
    rows[start[li] + p] = i;
  }
}

__global__ __launch_bounds__(256) void kpos2(const short* __restrict__ emb16,
                                             const int* __restrict__ lab,
                                             const int* __restrict__ hist,
                                             const int* __restrict__ start,
                                             const int* __restrict__ rows,
                                             float* __restrict__ pmin,
                                             float* __restrict__ pterm,
                                             int* __restrict__ valid) {
  int t = threadIdx.x;
  int wv = t >> 6, lane = t & 63;
  int i = blockIdx.x * 4 + wv;
  int li = lab[i];
  int s0 = start[li], c = hist[li];
  float ei[8];
  v8s e = *(const v8s*)(emb16 + (size_t)i * 512 + lane * 8);
#pragma unroll
  for (int k = 0; k < 8; ++k) ei[k] = bf2f(e[k]);
  float smin = 1e30f, ssum = 0.f;
  for (int k = 0; k < c; ++k) {
    int j = rows[s0 + k];
    if (j == i) continue;
    v8s f = *(const v8s*)(emb16 + (size_t)j * 512 + lane * 8);
    float s = 0.f;
#pragma unroll
    for (int q = 0; q < 8; ++q) s += ei[q] * bf2f(f[q]);
#pragma unroll
    for (int off = 32; off; off >>= 1) s += __shfl_xor(s, off);
    smin = fminf(smin, s);
    ssum += s;
  }
  if (lane == 0) {
    int pc = c - 1, nc = 8192 - c;
    pmin[i] = smin;                                   // +1e30 when no positives
    pterm[i] = ssum / (float)(pc > 0 ? pc : 1) / TEMPV;
    valid[i] = (pc > 0 && nc > 0) ? 1 : 0;
  }
}

// ---------------- main mining GEMM ----------------
// Grid 1024 = 128 row-blocks(BM=64) x 8 col-blocks (1024 cols; cb=bid&7 -> XCD).
// R panel (64 rows x 512 K bf16 = 64KB) LDS-resident; col K-tile Cg (128x64 = 16KB)
// staged per ks (XCD-local L2 panel). 4 waves x 16 rows each (l&15).
// acc[mi][r]: row = wv*16 + (l&15), col = colstart + mi*16 + (l>>4)*4 + r
// -> per-lane register SEMI top-16 mining (no all-neg list; fallback handles rare
// empty-semi rows exactly).
__global__ __launch_bounds__(256, 2) void kgemm(const short* __restrict__ emb16,
                                                const int* __restrict__ lab,
                                                const float* __restrict__ pminA,
                                                float* __restrict__ Lsemi) {
  __shared__ short Rs[64][64][8];     // [kchunk][row][8] = 64KB, resident
  __shared__ short Cg[8][128][8];     // col K-tile, 16KB

  int t = threadIdx.x;
  int bid = blockIdx.x;
  int rb = bid >> 3, cb = bid & 7;
  int rowbase = rb * 64;
  int colblock = cb * 1024;

  int wv = t >> 6, l = t & 63;
  int l15 = l & 15, l4 = l >> 4;

  int myrow = rowbase + wv * 16 + l15;
  int rlab = lab[myrow];
  float pm = pminA[myrow];

  float RS[16];
#pragma unroll
  for (int k = 0; k < 16; ++k) RS[k] = NEGV;

  // stage the resident R panel once: chunk-major [ch][row][8]
#pragma unroll
  for (int q = 0; q < 16; ++q) {
    int e = q * 256 + t;
    int ch = e >> 6, row = e & 63;
    gload16(emb16 + ((size_t)(rowbase + row) * 512 + ch * 8), &Rs[ch][row][0]);
  }

  for (int tile = 0; tile < 8; ++tile) {
    int colstart = colblock + tile * 128;
    v4f acc[8];
#pragma unroll
    for (int mi = 0; mi < 8; ++mi) acc[mi] = (v4f)0.f;

    for (int ks = 0; ks < 8; ++ks) {
      int kbase = ks * 64;
      __syncthreads();  // previous MFMA reads of Cg done before overwrite
#pragma unroll
      for (int q = 0; q < 4; ++q) {
        int e = q * 256 + t;
        int ch = e >> 7, idx = e & 127;
        gload16(emb16 + ((size_t)(colstart + idx) * 512 + kbase + ch * 8), &Cg[ch][idx][0]);
      }
      __syncthreads();
#pragma unroll
      for (int h = 0; h < 2; ++h) {
        v8s b = *(const v8s*)&Rs[ks * 8 + h * 4 + l4][wv * 16 + l15][0];
        v8s a[8];
#pragma unroll
        for (int mi = 0; mi < 8; ++mi)
          a[mi] = *(const v8s*)&Cg[h * 4 + l4][mi * 16 + l15][0];
#pragma unroll
        for (int mi = 0; mi < 8; ++mi)
          acc[mi] = __builtin_amdgcn_mfma_f32_16x16x32_bf16(a[mi], b, acc[mi], 0, 0, 0);
      }
    }

    // ---- per-lane semi-hard register mining ----
#pragma unroll
    for (int c = 0; c < 2; ++c) {
      int lc[4][4];
#pragma unroll
      for (int mm = 0; mm < 4; ++mm) {
        int4 q = *(const int4*)&lab[colstart + (c * 4 + mm) * 16 + l4 * 4];
        lc[mm][0] = q.x; lc[mm][1] = q.y; lc[mm][2] = q.z; lc[mm][3] = q.w;
      }
      float S[16];
#pragma unroll
      for (int j = 0; j < 16; ++j) {
        const int mi = c * 4 + (j >> 2), r = j & 3;
        float v = acc[mi][r];
        bool keep = (lc[j >> 2][r] != rlab) && (v < pm);
        S[j] = keep ? v : NEGV;
      }
      sort16d(S);
      mergeld(RS, S);
    }
  }

  // merge the 4 l4-lane groups holding the same row, write partials
  xmerge16(RS, 16);
  xmerge16(RS, 32);
  if (l4 == 0) {
    size_t o = ((size_t)cb * 8192 + myrow) * 16;
#pragma unroll
    for (int k = 0; k < 4; ++k)
      *(float4*)&Lsemi[o + k * 4] =
          make_float4(RS[k * 4], RS[k * 4 + 1], RS[k * 4 + 2], RS[k * 4 + 3]);
  }
}

// merge 8 col-block semi partials, masked LSE, detect fallback rows, reduce
__global__ __launch_bounds__(256) void kfin(const float* __restrict__ Lsemi,
                                            const float* __restrict__ pterm,
                                            const int* __restrict__ valid,
                                            float* lsum, int* nval,
                                            int* fbcnt, int* fbrows) {
  int i = blockIdx.x * 256 + threadIdx.x;
  float S[16], M[16];
#pragma unroll
  for (int k = 0; k < 16; ++k) S[k] = Lsemi[(size_t)i * 16 + k];
  for (int c = 1; c < 8; ++c) {
    size_t o = ((size_t)c * 8192 + i) * 16;
#pragma unroll
    for (int k = 0; k < 16; ++k) M[k] = Lsemi[o + k];
    mergeld(S, M);
  }
  int vd = valid[i];
  bool hs = S[0] > -1e29f;
  float li = 0.f;
  if (vd && !hs) {
    int idx = atomicAdd(fbcnt, 1);
    fbrows[idx] = i;          // loss added by kfallB
  } else if (vd) {
    float m = S[0] / TEMPV;
    float se = 0.f;
#pragma unroll
    for (int k = 0; k < 16; ++k)
      if (S[k] > -1e29f) se += expf(S[k] / TEMPV - m);
    li = m + logf(se) - pterm[i];
  }
#pragma unroll
  for (int off = 32; off; off >>= 1) {
    li += __shfl_xor(li, off);
    vd += __shfl_xor(vd, off);
  }
  __shared__ float rsd[4];
  __shared__ int rid[4];
  int wv = threadIdx.x >> 6;
  if ((threadIdx.x & 63) == 0) { rsd[wv] = li; rid[wv] = vd; }
  __syncthreads();
  if (threadIdx.x == 0) {
    atomicAdd(lsum, rsd[0] + rsd[1] + rsd[2] + rsd[3]);
    atomicAdd(nval, rid[0] + rid[1] + rid[2] + rid[3]);
  }
}

// Parallel fallback phase A: unit u = (f, j) -> row fbrows[f], candidates
// [j*256, j*256+256). One candidate per thread; block-top-16 via wave butterfly
// on wave 0; partial -> fbpart[f*32+j].
__global__ __launch_bounds__(256) void kfallA(const short* __restrict__ emb16,
                                              const int* __restrict__ lab,
                                              const int* __restrict__ fbcnt,
                                              const int* __restrict__ fbrows,
                                              float* __restrict__ fbpart) {
  int nfb = *fbcnt;
  if (nfb > 2048) nfb = 2048;
  int nunits = nfb * 32;
  __shared__ short remb[512];
  __shared__ float sims[256];
  int t = threadIdx.x;
  for (int u = blockIdx.x; u < nunits; u += gridDim.x) {
    int f = u >> 5, j = u & 31;
    int row = fbrows[f];
    int rl = lab[row];
    __syncthreads();  // prior iteration's reads of remb/sims complete
    if (t < 64) *(v8s*)&remb[t * 8] = *(const v8s*)(emb16 + (size_t)row * 512 + t * 8);
    __syncthreads();
    int c = j * 256 + t;
    float s = 0.f;
#pragma unroll 8
    for (int q = 0; q < 64; ++q) {
      v8s e = *(const v8s*)(emb16 + (size_t)c * 512 + q * 8);
      v8s r = *(const v8s*)&remb[q * 8];
#pragma unroll
      for (int z = 0; z < 8; ++z) s += bf2f(e[z]) * bf2f(r[z]);
    }
    sims[t] = (lab[c] != rl) ? s : NEGV;
    __syncthreads();
    if (t < 64) {
      float M[16];
#pragma unroll
      for (int k = 0; k < 16; ++k) M[k] = NEGV;
      M[0] = sims[t]; M[1] = sims[64 + t]; M[2] = sims[128 + t]; M[3] = sims[192 + t];
      sort16d(M);
      xmerge16(M, 1); xmerge16(M, 2); xmerge16(M, 4);
      xmerge16(M, 8); xmerge16(M, 16); xmerge16(M, 32);
      if (t == 0) {
#pragma unroll
        for (int k = 0; k < 16; ++k) fbpart[(size_t)(f * 32 + j) * 16 + k] = M[k];
      }
    }
  }
}

// Parallel fallback phase B: one thread per fallback row merges 32 partials,
// computes LSE, adds loss. Serial exact path only for f >= 2048 (never expected).
__global__ __launch_bounds__(256) void kfallB(const short* __restrict__ emb16,
                                              const int* __restrict__ lab,
                                              const int* __restrict__ fbcnt,
                                              const int* __restrict__ fbrows,
                                              const float* __restrict__ fbpart,
                                              const float* __restrict__ pterm,
                                              float* lsum) {
  int nfb = *fbcnt;
  int gid = blockIdx.x * 256 + threadIdx.x;
  for (int f = gid; f < nfb; f += gridDim.x * 256) {
    int row = fbrows[f];
    float R[16];
    if (f < 2048) {
#pragma unroll
      for (int k = 0; k < 16; ++k) R[k] = fbpart[(size_t)(f * 32) * 16 + k];
      for (int j = 1; j < 32; ++j) {
        float M[16];
#pragma unroll
        for (int k = 0; k < 16; ++k) M[k] = fbpart[(size_t)(f * 32 + j) * 16 + k];
        mergeld(R, M);
      }
    } else {
      // correctness guard; never expected to execute
      int rl = lab[row];
      float L[16];
#pragma unroll
      for (int k = 0; k < 16; ++k) L[k] = NEGV;
      for (int c = 0; c < 8192; ++c) {
        if (lab[c] == rl) continue;
        float s = 0.f;
        for (int q = 0; q < 64; ++q) {
          v8s e = *(const v8s*)(emb16 + (size_t)c * 512 + q * 8);
          v8s r = *(const v8s*)(emb16 + (size_t)row * 512 + q * 8);
#pragma unroll
          for (int z = 0; z < 8; ++z) s += bf2f(e[z]) * bf2f(r[z]);
        }
        if (s > L[0]) ins16(L, s);
      }
#pragma unroll
      for (int k = 0; k < 16; ++k) R[k] = L[15 - k];
    }
    float m = R[0] / TEMPV;
    float se = 0.f;
#pragma unroll
    for (int k = 0; k < 16; ++k)
      if (R[k] > -1e29f) se += expf(R[k] / TEMPV - m);
    float lse = m + logf(se);
    atomicAdd(lsum, lse - pterm[row]);
  }
}

__global__ void kout(const float* lsum, const int* nval, float* out) {
  if (threadIdx.x == 0 && blockIdx.x == 0)
    out[0] = lsum[0] / (float)(nval[0] > 0 ? nval[0] : 1);
}

extern "C" void kernel_launch(void* const* d_in, const int* in_sizes, int n_in,
                              void* d_out, int out_size, void* d_ws, size_t ws_size,
                              hipStream_t stream) {
  const float* emb = (const float*)d_in[0];
  const int* lab = (const int*)d_in[1];
  float* out = (float*)d_out;

  char* wsb = (char*)d_ws;
  short* emb16 = (short*)wsb;                       // 8,388,608
  int* hist = (int*)(wsb + 8388608);                // 8,192
  int* cur = (int*)(wsb + 8396800);                 // 8,192
  int* start = (int*)(wsb + 8404992);               // 8,192
  int* rows = (int*)(wsb + 8413184);                // 32,768
  float* pmin = (float*)(wsb + 8445952);            // 32,768
  float* pterm = (float*)(wsb + 8478720);           // 32,768
  int* valid = (int*)(wsb + 8511488);               // 32,768
  float* LsemiW = (float*)(wsb + 8544256);          // 4,194,304
  int* fbcnt = (int*)(wsb + 12738560);              // 4 (+pad 64)
  int* fbrows = (int*)(wsb + 12738624);             // 32,768
  float* fbpart = (float*)(wsb + 12771392);         // 4,194,304 (2048*32*16 f32)
  float* lsum = (float*)(wsb + 16965696);           // 4
  int* nval = (int*)(wsb + 16965700);               // 4

  kinit<<<8, 256, 0, stream>>>(hist, cur, lsum, nval, fbcnt);
  kconv<<<4096, 256, 0, stream>>>(emb, emb16);
  khist<<<32, 256, 0, stream>>>(lab, hist);
  kprefix<<<1, 256, 0, stream>>>(hist, start);
  kscatter<<<32, 256, 0, stream>>>(lab, start, cur, rows);
  kpos2<<<2048, 256, 0, stream>>>(emb16, lab, hist, start, rows, pmin, pterm, valid);
  kgemm<<<1024, 256, 0, stream>>>(emb16, lab, pmin, LsemiW);
  kfin<<<32, 256, 0, stream>>>(LsemiW, pterm, valid, lsum, nval, fbcnt, fbrows);
  kfallA<<<256, 256, 0, stream>>>(emb16, lab, fbcnt, fbrows, fbpart);
  kfallB<<<32, 256, 0, stream>>>(emb16, lab, fbcnt, fbrows, fbpart, pterm, lsum);
  kout<<<1, 64, 0, stream>>>(lsum, nval, out);
}